// Round 1
// baseline (435.484 us; speedup 1.0000x reference)
//
#include <hip/hip_runtime.h>

#define NB    2048
#define NTOK  49
#define N1    50
#define DIMC  256
#define NHEAD 8
#define NWIN  64

typedef short s16x8 __attribute__((ext_vector_type(8)));
typedef float f32x4 __attribute__((ext_vector_type(4)));

__device__ __forceinline__ unsigned short f2bf(float f) {
    unsigned int u = __builtin_bit_cast(unsigned int, f);
    u = (u + 0x7FFFu + ((u >> 16) & 1u)) >> 16;
    return (unsigned short)u;
}

__device__ __forceinline__ s16x8 ld8(const unsigned short* p) {
    return *(const s16x8*)p;   // caller guarantees 16B alignment
}

// ---------------- prep: transpose + bf16-convert weights ----------------
__global__ void prep_kernel(const float* __restrict__ qkv_w, const float* __restrict__ proj_w,
                            unsigned short* __restrict__ wqkvT, unsigned short* __restrict__ wprojT) {
    int idx = blockIdx.x * 256 + threadIdx.x;           // 0 .. 768*256-1
    if (idx < 768 * 256) {
        int n = idx >> 8, k = idx & 255;
        wqkvT[idx] = f2bf(qkv_w[k * 768 + n]);          // wqkvT[n][k]
    }
    if (idx < 256 * 256) {
        int n = idx >> 8, k = idx & 255;
        wprojT[idx] = f2bf(proj_w[k * 256 + n]);        // wprojT[n][k]
    }
}

// ---------------- fused QKV + attention, one block per batch ----------------
// LDS budget: 33792 + 10240 + 10240 + 9216 + 18432 = 81920 B -> 2 blocks/CU
__global__ __launch_bounds__(512, 4) void attn_kernel(
        const float* __restrict__ x, const float* __restrict__ mask,
        const float* __restrict__ cls, const float* __restrict__ qkv_b,
        const unsigned short* __restrict__ wqkvT, unsigned short* __restrict__ attO) {
    __shared__ unsigned short sXC[64 * 264];   // xc bf16, rows 0..49 valid, 50..63 zero
    __shared__ unsigned short sQ [2 * 64 * 40];  // per group: 2 heads, [64 tok][32 d], stride 40
    __shared__ unsigned short sK [2 * 64 * 40];
    __shared__ unsigned short sVT[2 * 32 * 72];  // v transposed: [32 d][64 tok], stride 72
    __shared__ unsigned short sU [8 * 16 * 72];  // union: sW (32x264=8448) | sP (8 waves x 16x72)

    const int b    = blockIdx.x;
    const int tid  = threadIdx.x;
    const int lane = tid & 63;
    const int w    = tid >> 6;       // wave 0..7
    const int ln15 = lane & 15;
    const int quad = lane >> 4;
    const int q8   = quad * 8;
    const int win  = b & (NWIN - 1);
    const float SCALE = 0.17677669529663687f;   // 32^-0.5

    // ---- stage xc: row0 = class token, rows 1..49 = x, rows 50..63 = 0
    for (int i = 0; i < 32; ++i) {
        int idx = i * 512 + tid;
        int r = idx >> 8, c = idx & 255;
        float v;
        if (r == 0)            v = cls[c];
        else if (r <= NTOK)    v = x[((size_t)b * NTOK + (r - 1)) * DIMC + c];
        else                   v = 0.0f;
        sXC[r * 264 + c] = f2bf(v);
    }
    __syncthreads();

    unsigned short* sW = sU;

    for (int g = 0; g < 4; ++g) {   // head-pair groups: heads 2g, 2g+1
        // ================= phase 1: qkv slice GEMM =================
        const int mt  = w & 3;      // M-tile (rows mt*16..)
        const int ntw = w >> 2;     // N-tile within 32-col chunk
        for (int c = 0; c < 6; ++c) {
            const int span = c >> 1;            // 0=q,1=k,2=v
            const int base = span * 256 + g * 64 + (c & 1) * 32;
            // stage sW: 32 output-cols x 256 k   (bf16, stride 264)
            {
                const unsigned int* wsrc = (const unsigned int*)wqkvT + (size_t)base * 128;
                unsigned int* wdst = (unsigned int*)sW;
                for (int i = 0; i < 8; ++i) {
                    int idx = i * 512 + tid;
                    int r = idx >> 7, cc = idx & 127;
                    wdst[r * 132 + cc] = wsrc[r * 128 + cc];
                }
            }
            __syncthreads();
            // one 16x16 tile per wave, K = 256
            f32x4 acc = {0.f, 0.f, 0.f, 0.f};
            const unsigned short* arow = &sXC[(mt * 16 + ln15) * 264];
            const unsigned short* brow = &sW [(ntw * 16 + ln15) * 264];
            #pragma unroll
            for (int ks = 0; ks < 8; ++ks) {
                s16x8 a  = ld8(arow + ks * 32 + q8);
                s16x8 bb = ld8(brow + ks * 32 + q8);
                acc = __builtin_amdgcn_mfma_f32_16x16x32_bf16(a, bb, acc, 0, 0, 0);
            }
            // epilogue: bias (+scale for q), scatter into sQ/sK/sVT
            const int gcol = base + ntw * 16 + ln15;
            const int type = gcol >> 8;            // 0=q 1=k 2=v (wave-uniform)
            const int hl   = (gcol >> 5) & 1;      // head within group
            const int d    = gcol & 31;
            const float bias = qkv_b[gcol];
            const int m0 = mt * 16 + quad * 4;
            #pragma unroll
            for (int i = 0; i < 4; ++i) {
                float v = acc[i] + bias;
                int m = m0 + i;
                if (type == 0)      sQ[(hl * 64 + m) * 40 + d] = f2bf(v * SCALE);
                else if (type == 1) sK[(hl * 64 + m) * 40 + d] = f2bf(v);
                else                sVT[(hl * 32 + d) * 72 + m] = f2bf(v);
            }
            __syncthreads();
        }

        // ================= phase 2: attention, one (head, row-tile) per wave =================
        {
            const int hl  = w & 1;
            const int hg  = g * 2 + hl;
            const int mtg = w >> 1;              // row tile 0..3
            // scores S = q k^T  (K=32 -> single MFMA per tile)
            f32x4 s[4];
            s16x8 a = ld8(&sQ[(hl * 64 + mtg * 16 + ln15) * 40 + q8]);
            #pragma unroll
            for (int nt = 0; nt < 4; ++nt) {
                s16x8 bb = ld8(&sK[(hl * 64 + nt * 16 + ln15) * 40 + q8]);
                f32x4 z = {0.f, 0.f, 0.f, 0.f};
                s[nt] = __builtin_amdgcn_mfma_f32_16x16x32_bf16(a, bb, z, 0, 0, 0);
            }
            // mask + softmax (rows live in 16-lane quads; cols: 16 lanes x 4 reg-tiles)
            const int r0 = mtg * 16 + quad * 4;
            float invsum[4];
            #pragma unroll
            for (int i = 0; i < 4; ++i) {
                int r = r0 + i;
                #pragma unroll
                for (int nt = 0; nt < 4; ++nt) {
                    int cgl = nt * 16 + ln15;
                    float v = s[nt][i];
                    if (cgl < N1) {
                        if (r < N1) v += mask[((size_t)win * N1 + r) * N1 + cgl];
                    } else v = -1e30f;
                    s[nt][i] = v;
                }
                float mx = fmaxf(fmaxf(s[0][i], s[1][i]), fmaxf(s[2][i], s[3][i]));
                #pragma unroll
                for (int off = 1; off < 16; off <<= 1) mx = fmaxf(mx, __shfl_xor(mx, off, 64));
                float sum = 0.f;
                #pragma unroll
                for (int nt = 0; nt < 4; ++nt) {
                    float e = __expf(s[nt][i] - mx);
                    s[nt][i] = e;
                    sum += e;
                }
                #pragma unroll
                for (int off = 1; off < 16; off <<= 1) sum += __shfl_xor(sum, off, 64);
                invsum[i] = 1.0f / sum;
            }
            // P -> LDS (A-operand layout round-trip), per-wave private region
            unsigned short* sP = &sU[w * 16 * 72];
            #pragma unroll
            for (int i = 0; i < 4; ++i) {
                int lr = quad * 4 + i;
                #pragma unroll
                for (int nt = 0; nt < 4; ++nt)
                    sP[lr * 72 + nt * 16 + ln15] = f2bf(s[nt][i]);
            }
            __syncthreads();
            // O = P V   (M=16, N=32, K=64)
            f32x4 o[2] = {{0.f,0.f,0.f,0.f}, {0.f,0.f,0.f,0.f}};
            #pragma unroll
            for (int ks = 0; ks < 2; ++ks) {
                s16x8 pa = ld8(&sP[ln15 * 72 + ks * 32 + q8]);
                #pragma unroll
                for (int nt = 0; nt < 2; ++nt) {
                    s16x8 vb = ld8(&sVT[(hl * 32 + nt * 16 + ln15) * 72 + ks * 32 + q8]);
                    o[nt] = __builtin_amdgcn_mfma_f32_16x16x32_bf16(pa, vb, o[nt], 0, 0, 0);
                }
            }
            // write attn-out (bf16) with 1/rowsum
            #pragma unroll
            for (int i = 0; i < 4; ++i) {
                int r = r0 + i;
                if (r < N1) {
                    #pragma unroll
                    for (int nt = 0; nt < 2; ++nt) {
                        int dcol = nt * 16 + ln15;
                        attO[((size_t)b * N1 + r) * DIMC + hg * 32 + dcol] = f2bf(o[nt][i] * invsum[i]);
                    }
                }
            }
        }
        __syncthreads();   // before next group's phase 1 overwrites sQ/sK/sVT/sU
    }
}

// ---------------- proj GEMM: (102400 x 256) @ (256 x 256) + bias, split write ----------------
__global__ __launch_bounds__(256, 2) void proj_kernel(
        const unsigned short* __restrict__ attO, const unsigned short* __restrict__ wprojT,
        const float* __restrict__ proj_b, float* __restrict__ out) {
    __shared__ unsigned short sA[64 * 264];
    __shared__ unsigned short sB[64 * 264];
    const int blk  = blockIdx.x;
    const int tid  = threadIdx.x;
    const int lane = tid & 63;
    const int w    = tid >> 6;
    const int ln15 = lane & 15;
    const int quad = lane >> 4;
    const int q8   = quad * 8;
    const size_t rbase = (size_t)blk * 64;

    {   // stage A rows (bf16 already)
        const unsigned int* src = (const unsigned int*)attO + rbase * 128;
        unsigned int* dst = (unsigned int*)sA;
        for (int i = 0; i < 32; ++i) {
            int idx = i * 256 + tid;
            int r = idx >> 7, c = idx & 127;
            dst[r * 132 + c] = src[r * 128 + c];
        }
    }
    for (int ch = 0; ch < 4; ++ch) {
        __syncthreads();   // sA ready / prev sB consumers done
        {
            const unsigned int* src = (const unsigned int*)wprojT + (size_t)ch * 64 * 128;
            unsigned int* dst = (unsigned int*)sB;
            for (int i = 0; i < 32; ++i) {
                int idx = i * 256 + tid;
                int r = idx >> 7, c = idx & 127;
                dst[r * 132 + c] = src[r * 128 + c];
            }
        }
        __syncthreads();
        f32x4 acc[4];
        #pragma unroll
        for (int nt = 0; nt < 4; ++nt) acc[nt] = f32x4{0.f, 0.f, 0.f, 0.f};
        const unsigned short* arow = &sA[(w * 16 + ln15) * 264];
        #pragma unroll
        for (int ks = 0; ks < 8; ++ks) {
            s16x8 a = ld8(arow + ks * 32 + q8);
            #pragma unroll
            for (int nt = 0; nt < 4; ++nt) {
                s16x8 bb = ld8(&sB[(nt * 16 + ln15) * 264 + ks * 32 + q8]);
                acc[nt] = __builtin_amdgcn_mfma_f32_16x16x32_bf16(a, bb, acc[nt], 0, 0, 0);
            }
        }
        const int m0 = w * 16 + quad * 4;
        #pragma unroll
        for (int nt = 0; nt < 4; ++nt) {
            int gcol = ch * 64 + nt * 16 + ln15;
            float bias = proj_b[gcol];
            #pragma unroll
            for (int i = 0; i < 4; ++i) {
                size_t R = rbase + m0 + i;
                unsigned int bidx = (unsigned int)(R / 50u);
                unsigned int t    = (unsigned int)(R % 50u);
                float v = acc[nt][i] + bias;
                if (t == 0) out[(size_t)bidx * 256 + gcol] = v;
                else        out[(size_t)524288 + ((size_t)bidx * 49 + (t - 1)) * 256 + gcol] = v;
            }
        }
    }
}

extern "C" void kernel_launch(void* const* d_in, const int* in_sizes, int n_in,
                              void* d_out, int out_size, void* d_ws, size_t ws_size,
                              hipStream_t stream) {
    const float* x      = (const float*)d_in[0];
    const float* mask   = (const float*)d_in[1];
    const float* cls    = (const float*)d_in[2];
    const float* qkv_w  = (const float*)d_in[3];
    const float* qkv_b  = (const float*)d_in[4];
    const float* proj_w = (const float*)d_in[5];
    const float* proj_b = (const float*)d_in[6];
    float* out = (float*)d_out;

    // workspace layout
    unsigned short* attO   = (unsigned short*)d_ws;                               // 52,428,800 B
    unsigned short* wqkvT  = (unsigned short*)((char*)d_ws + 52428800);           //    393,216 B
    unsigned short* wprojT = (unsigned short*)((char*)d_ws + 52428800 + 393216);  //    131,072 B

    prep_kernel<<<768, 256, 0, stream>>>(qkv_w, proj_w, wqkvT, wprojT);
    attn_kernel<<<NB, 512, 0, stream>>>(x, mask, cls, qkv_b, wqkvT, attO);
    proj_kernel<<<(NB * N1) / 64, 256, 0, stream>>>(attO, wprojT, proj_b, out);
}

// Round 3
// 318.469 us; speedup vs baseline: 1.3674x; 1.3674x over previous
//
#include <hip/hip_runtime.h>

#define NB    2048
#define N1    50
#define DIMC  256
#define NHEAD 8

typedef short  s16x8 __attribute__((ext_vector_type(8)));
typedef short  s16x4 __attribute__((ext_vector_type(4)));
typedef float  f32x4 __attribute__((ext_vector_type(4)));
typedef float  f32x2 __attribute__((ext_vector_type(2)));

__device__ __forceinline__ unsigned short f2bf(float f) {
    unsigned int u = __builtin_bit_cast(unsigned int, f);
    u = (u + 0x7FFFu + ((u >> 16) & 1u)) >> 16;
    return (unsigned short)u;
}
__device__ __forceinline__ s16x8 ld8(const unsigned short* p) {
    return *(const s16x8*)p;   // 16B-aligned by construction
}
// async global->LDS, 16B per lane; lds base must be wave-uniform
__device__ __forceinline__ void gll16(const unsigned short* g, unsigned short* l) {
    __builtin_amdgcn_global_load_lds(
        (const __attribute__((address_space(1))) unsigned int*)g,
        (__attribute__((address_space(3))) unsigned int*)l, 16, 0, 0);
}

// ---------------- prep: K-blocked bf16 weights + padded mask ----------------
// wqkvB[ks][n][kk] = qkv_w[ks*32+kk][n]   (8 x 768 x 32 bf16, contiguous per ks)
// wprojB[ks][n][kk] = proj_w[ks*32+kk][n] (8 x 256 x 32 bf16)
// maskP[win][q][k]  (64x64x64 f32): pad keys k>=50 -> -1e30 (exp->0); pad queries -> 0
__global__ void prep_kernel(const float* __restrict__ qkv_w, const float* __restrict__ proj_w,
                            const float* __restrict__ mask,
                            unsigned short* __restrict__ wqkvB, unsigned short* __restrict__ wprojB,
                            float* __restrict__ maskP) {
    int idx = blockIdx.x * 256 + threadIdx.x;          // 0 .. 262143
    {
        int wv = idx >> 12, q = (idx >> 6) & 63, k = idx & 63;
        float v = (k < 50) ? ((q < 50) ? mask[(wv * 50 + q) * 50 + k] : 0.f) : -1e30f;
        maskP[idx] = v;
    }
    if (idx < 196608) {
        int ks = idx / 24576, rem = idx - ks * 24576, n = rem >> 5, kk = rem & 31;
        wqkvB[idx] = f2bf(qkv_w[(ks * 32 + kk) * 768 + n]);
    }
    if (idx < 65536) {
        int ks = idx >> 13, rem = idx & 8191, n = rem >> 5, kk = rem & 31;
        wprojB[idx] = f2bf(proj_w[(ks * 32 + kk) * 256 + n]);
    }
}

// ---------------- fused QKV GEMM + attention, one batch per block ----------------
// 1024 threads = 16 waves. LDS union 155648 B -> 1 block/CU (16 waves/CU).
// Phase 1: [64x256] @ [256x768], BK=32, dbuf global_load_lds B-staging. 10 barriers total.
// Phase 2: wave = (head, row-half); S^T = MFMA(A=K,B=Q); no-max softmax (2 shuffles);
//          P via conflict-free b64 LDS round-trip (same-wave DS order + lgkmcnt fence);
//          O^T = MFMA(A=V^T, B=P); packed 8B stores.
__global__ __launch_bounds__(1024, 4) void attn_kernel(
        const float* __restrict__ x, const float* __restrict__ cls,
        const float* __restrict__ qkv_b, const unsigned short* __restrict__ wqkvB,
        const float* __restrict__ maskP, unsigned short* __restrict__ attO) {
    __shared__ __align__(16) char smem_raw[155648];
    unsigned short* S   = (unsigned short*)smem_raw;
    // phase-2 region (aliases phase-1 region; time-disjoint via barriers)
    unsigned short* sQ  = S;            // [8][64][40] bf16, scaled+biased
    unsigned short* sK  = S + 20480;    // [8][64][40]
    unsigned short* sVT = S + 40960;    // [8][32][72]  v transposed [d][tok]
    unsigned short* sP  = S + 59392;    // [16 waves][16][72]
    // phase-1 region
    unsigned short* sXC = S;            // [64][264] bf16 xc
    unsigned short* sB0 = S + 16896;    // [768][32] bf16   (byte 33792)
    unsigned short* sB1 = S + 41472;    //                  (byte 82944)

    const int b = blockIdx.x, tid = threadIdx.x;
    const int lane = tid & 63, w = tid >> 6;
    const int ln15 = lane & 15, quad = lane >> 4, q8 = quad * 8;
    const int wm = w & 1, wn = w >> 1;      // phase-1 wave grid: 2 (rows) x 8 (cols of 96)
    const int win = b & 63;
    const float SCALE = 0.17677669529663687f;

    // ---- stage xc rows (row0=cls, 1..49=x, 50..63=0), paired u32 LDS writes
    #pragma unroll
    for (int i = 0; i < 8; ++i) {
        int p = i * 1024 + tid;
        int r = p >> 7, c = (p & 127) * 2;
        float v0, v1;
        if (r == 0)       { v0 = cls[c]; v1 = cls[c + 1]; }
        else if (r <= 49) { const float* px = &x[((size_t)b * 49 + (r - 1)) * 256 + c];
                            f32x2 t = *(const f32x2*)px; v0 = t[0]; v1 = t[1]; }
        else              { v0 = 0.f; v1 = 0.f; }
        *(unsigned int*)&sXC[r * 264 + c] = (unsigned int)f2bf(v0) | ((unsigned int)f2bf(v1) << 16);
    }
    // ---- prefetch B-chunk ks=0
    #pragma unroll
    for (int i = 0; i < 3; ++i) {
        int sb = w * 192 + i * 64;
        gll16(wqkvB + (sb + lane) * 8, sB0 + sb * 8);
    }
    __syncthreads();

    f32x4 acc[2][6];
    #pragma unroll
    for (int mt = 0; mt < 2; ++mt)
        #pragma unroll
        for (int nt = 0; nt < 6; ++nt) acc[mt][nt] = f32x4{0.f, 0.f, 0.f, 0.f};

    // ---- K-loop: 8 steps of BK=32, sB double-buffered
    for (int ks = 0; ks < 8; ++ks) {
        unsigned short* bb = (ks & 1) ? sB1 : sB0;
        if (ks < 7) {
            unsigned short* nb = (ks & 1) ? sB0 : sB1;
            const unsigned short* src = wqkvB + (ks + 1) * 24576;
            #pragma unroll
            for (int i = 0; i < 3; ++i) {
                int sb = w * 192 + i * 64;
                gll16(src + (sb + lane) * 8, nb + sb * 8);
            }
        }
        s16x8 af[2], bf[6];
        #pragma unroll
        for (int mt = 0; mt < 2; ++mt)
            af[mt] = ld8(&sXC[(wm * 32 + mt * 16 + ln15) * 264 + ks * 32 + q8]);
        #pragma unroll
        for (int nt = 0; nt < 6; ++nt)
            bf[nt] = ld8(&bb[(wn * 96 + nt * 16 + ln15) * 32 + q8]);
        #pragma unroll
        for (int mt = 0; mt < 2; ++mt)
            #pragma unroll
            for (int nt = 0; nt < 6; ++nt)
                acc[mt][nt] = __builtin_amdgcn_mfma_f32_16x16x32_bf16(af[mt], bf[nt], acc[mt][nt], 0, 0, 0);
        __syncthreads();
    }

    // ---- epilogue: bias (+scale for q), scatter into sQ/sK, packed b64 into sVT
    #pragma unroll
    for (int mt = 0; mt < 2; ++mt) {
        const int tokb = wm * 32 + mt * 16 + quad * 4;
        #pragma unroll
        for (int nt = 0; nt < 6; ++nt) {
            const int gc = wn * 96 + nt * 16 + ln15;
            const int type = gc >> 8;             // wave-uniform per nt
            const int hd = (gc >> 5) & 7, dd = gc & 31;
            const float bias = qkv_b[gc];
            if (type == 0) {
                #pragma unroll
                for (int i = 0; i < 4; ++i)
                    sQ[hd * 2560 + (tokb + i) * 40 + dd] = f2bf((acc[mt][nt][i] + bias) * SCALE);
            } else if (type == 1) {
                #pragma unroll
                for (int i = 0; i < 4; ++i)
                    sK[hd * 2560 + (tokb + i) * 40 + dd] = f2bf(acc[mt][nt][i] + bias);
            } else {
                s16x4 pk;
                #pragma unroll
                for (int i = 0; i < 4; ++i) pk[i] = f2bf(acc[mt][nt][i] + bias);
                *(s16x4*)&sVT[hd * 2304 + dd * 72 + tokb] = pk;   // v^T[d][tok], 4 toks packed
            }
        }
    }
    __syncthreads();

    // ---- attention: wave = (head h, row-half rh); queries (qt0+mt)*16+ln15
    const int h = w >> 1, rh = w & 1, qt0 = rh * 2;
    unsigned short* sPw = sP + w * 1152;

    s16x8 ak[4];
    #pragma unroll
    for (int kt = 0; kt < 4; ++kt)
        ak[kt] = ld8(&sK[h * 2560 + (kt * 16 + ln15) * 40 + q8]);

    f32x4 st[2][4];
    #pragma unroll
    for (int mt = 0; mt < 2; ++mt) {
        s16x8 bq = ld8(&sQ[h * 2560 + ((qt0 + mt) * 16 + ln15) * 40 + q8]);
        #pragma unroll
        for (int kt = 0; kt < 4; ++kt) {
            f32x4 z = {0.f, 0.f, 0.f, 0.f};
            st[mt][kt] = __builtin_amdgcn_mfma_f32_16x16x32_bf16(ak[kt], bq, z, 0, 0, 0);
        }
    }
    // S^T layout: col(=lane&15)=query, row(=quad*4+reg)=key.
    s16x8 pb[2][2];
    #pragma unroll
    for (int mt = 0; mt < 2; ++mt) {
        float sum = 0.f;
        #pragma unroll
        for (int kt = 0; kt < 4; ++kt) {
            f32x4 mk = *(const f32x4*)&maskP[((size_t)(win * 64 + (qt0 + mt) * 16 + ln15)) * 64 + kt * 16 + quad * 4];
            #pragma unroll
            for (int i = 0; i < 4; ++i) {
                float e = __expf(st[mt][kt][i] + mk[i]);   // no-max softmax; pad keys get -1e30 -> 0
                st[mt][kt][i] = e;
                sum += e;
            }
        }
        sum += __shfl_xor(sum, 16, 64);
        sum += __shfl_xor(sum, 32, 64);
        const float inv = 1.f / sum;
        #pragma unroll
        for (int kt = 0; kt < 4; ++kt) {
            s16x4 pk;
            #pragma unroll
            for (int i = 0; i < 4; ++i) pk[i] = f2bf(st[mt][kt][i] * inv);
            *(s16x4*)&sPw[ln15 * 72 + kt * 16 + quad * 4] = pk;   // P[query][key], conflict-free b64
        }
        // same-wave DS pipe is in-order; fence completion + stop compiler motion
        asm volatile("s_waitcnt lgkmcnt(0)" ::: "memory");
        pb[mt][0] = ld8(&sPw[ln15 * 72 + q8]);        // B-frag: P[query=ln15][key=q8+j]
        pb[mt][1] = ld8(&sPw[ln15 * 72 + 32 + q8]);
    }
    // O^T = V^T @ P^T : A-frag from sVT rows, B-frag = pb. C/D: col=query, row=d.
    s16x8 av[2][2];
    #pragma unroll
    for (int dt = 0; dt < 2; ++dt)
        #pragma unroll
        for (int kk = 0; kk < 2; ++kk)
            av[dt][kk] = ld8(&sVT[h * 2304 + (dt * 16 + ln15) * 72 + kk * 32 + q8]);
    f32x4 o[2][2];
    #pragma unroll
    for (int mt = 0; mt < 2; ++mt)
        #pragma unroll
        for (int dt = 0; dt < 2; ++dt) o[mt][dt] = f32x4{0.f, 0.f, 0.f, 0.f};
    #pragma unroll
    for (int mt = 0; mt < 2; ++mt)
        #pragma unroll
        for (int dt = 0; dt < 2; ++dt)
            #pragma unroll
            for (int kk = 0; kk < 2; ++kk)
                o[mt][dt] = __builtin_amdgcn_mfma_f32_16x16x32_bf16(av[dt][kk], pb[mt][kk], o[mt][dt], 0, 0, 0);
    #pragma unroll
    for (int mt = 0; mt < 2; ++mt) {
        const int qg = (qt0 + mt) * 16 + ln15;
        if (qg < N1) {
            #pragma unroll
            for (int dt = 0; dt < 2; ++dt) {
                s16x4 pk;
                #pragma unroll
                for (int i = 0; i < 4; ++i) pk[i] = f2bf(o[mt][dt][i]);
                *(s16x4*)&attO[((size_t)b * N1 + qg) * 256 + h * 32 + dt * 16 + quad * 4] = pk;
            }
        }
    }
}

// ---------------- proj GEMM: (102400 x 256) @ (256 x 256) + bias, split write ----------------
// 512 thr = 8 waves; BM=128, BN=256, BK=32 x8; dbuf global_load_lds A and B. 2 blocks/CU.
// A-tile slot map: 128 rows x 32 cols = 512 x 16B slots; slot s -> row=s>>2, part=s&3.
__global__ __launch_bounds__(512, 4) void proj_kernel(
        const unsigned short* __restrict__ attO, const unsigned short* __restrict__ wprojB,
        const float* __restrict__ proj_b, float* __restrict__ out) {
    __shared__ __align__(16) char smem_raw[49152];
    unsigned short* S   = (unsigned short*)smem_raw;
    unsigned short* sA0 = S;              // [128][32]
    unsigned short* sA1 = S + 4096;
    unsigned short* sB0 = S + 8192;       // [256][32]
    unsigned short* sB1 = S + 16384;

    const int blk = blockIdx.x, tid = threadIdx.x;
    const int lane = tid & 63, w = tid >> 6;
    const int ln15 = lane & 15, quad = lane >> 4, q8 = quad * 8;
    const int wm = w >> 1, wn = w & 1;    // wave grid 4 x 2; wave-tile 32 x 128
    const size_t rbase = (size_t)blk * 128;

    const int s   = w * 64 + lane;        // 0..511
    const int arow = s >> 2, apart = s & 3;

    // prefetch ks=0
    {
        gll16(attO + (rbase + arow) * 256 + apart * 8, sA0 + (w * 64) * 8);
        #pragma unroll
        for (int i = 0; i < 2; ++i) {                // B: 1024 slots, contiguous copy
            int sb = i * 512 + w * 64;
            gll16(wprojB + (sb + lane) * 8, sB0 + sb * 8);
        }
    }
    __syncthreads();

    f32x4 acc[2][8];
    #pragma unroll
    for (int mt = 0; mt < 2; ++mt)
        #pragma unroll
        for (int nt = 0; nt < 8; ++nt) acc[mt][nt] = f32x4{0.f, 0.f, 0.f, 0.f};

    for (int ks = 0; ks < 8; ++ks) {
        unsigned short* a = (ks & 1) ? sA1 : sA0;
        unsigned short* bbuf = (ks & 1) ? sB1 : sB0;
        if (ks < 7) {
            unsigned short* na = (ks & 1) ? sA0 : sA1;
            unsigned short* nb = (ks & 1) ? sB0 : sB1;
            gll16(attO + (rbase + arow) * 256 + (ks + 1) * 32 + apart * 8, na + (w * 64) * 8);
            const unsigned short* src = wprojB + (ks + 1) * 8192;
            #pragma unroll
            for (int i = 0; i < 2; ++i) {
                int sb = i * 512 + w * 64;
                gll16(src + (sb + lane) * 8, nb + sb * 8);
            }
        }
        s16x8 af[2], bf[8];
        #pragma unroll
        for (int mt = 0; mt < 2; ++mt)
            af[mt] = ld8(&a[(wm * 32 + mt * 16 + ln15) * 32 + q8]);
        #pragma unroll
        for (int nt = 0; nt < 8; ++nt)
            bf[nt] = ld8(&bbuf[(wn * 128 + nt * 16 + ln15) * 32 + q8]);
        #pragma unroll
        for (int mt = 0; mt < 2; ++mt)
            #pragma unroll
            for (int nt = 0; nt < 8; ++nt)
                acc[mt][nt] = __builtin_amdgcn_mfma_f32_16x16x32_bf16(af[mt], bf[nt], acc[mt][nt], 0, 0, 0);
        __syncthreads();
    }

    #pragma unroll
    for (int mt = 0; mt < 2; ++mt) {
        #pragma unroll
        for (int nt = 0; nt < 8; ++nt) {
            const int gc = wn * 128 + nt * 16 + ln15;
            const float bias = proj_b[gc];
            #pragma unroll
            for (int i = 0; i < 4; ++i) {
                unsigned int R = (unsigned int)rbase + wm * 32 + mt * 16 + quad * 4 + i;
                unsigned int bidx = R / 50u, t = R % 50u;
                float v = acc[mt][nt][i] + bias;
                if (t == 0) out[(size_t)bidx * 256 + gc] = v;
                else        out[(size_t)524288 + ((size_t)bidx * 49 + (t - 1)) * 256 + gc] = v;
            }
        }
    }
}

extern "C" void kernel_launch(void* const* d_in, const int* in_sizes, int n_in,
                              void* d_out, int out_size, void* d_ws, size_t ws_size,
                              hipStream_t stream) {
    const float* x      = (const float*)d_in[0];
    const float* mask   = (const float*)d_in[1];
    const float* cls    = (const float*)d_in[2];
    const float* qkv_w  = (const float*)d_in[3];
    const float* qkv_b  = (const float*)d_in[4];
    const float* proj_w = (const float*)d_in[5];
    const float* proj_b = (const float*)d_in[6];
    float* out = (float*)d_out;

    // workspace layout
    unsigned short* attO   = (unsigned short*)d_ws;                               // 52,428,800 B
    unsigned short* wqkvB  = (unsigned short*)((char*)d_ws + 52428800);           //    393,216 B
    unsigned short* wprojB = (unsigned short*)((char*)d_ws + 52822016);           //    131,072 B
    float*          maskP  = (float*)((char*)d_ws + 52953088);                    //  1,048,576 B

    prep_kernel<<<1024, 256, 0, stream>>>(qkv_w, proj_w, mask, wqkvB, wprojB, maskP);
    attn_kernel<<<NB, 1024, 0, stream>>>(x, cls, qkv_b, wqkvB, maskP, attO);
    proj_kernel<<<800, 512, 0, stream>>>(attO, wprojB, proj_b, out);
}

// Round 4
// 311.184 us; speedup vs baseline: 1.3994x; 1.0234x over previous
//
#include <hip/hip_runtime.h>

#define NB    2048
#define N1    50
#define DIMC  256
#define NHEAD 8

typedef short  s16x8 __attribute__((ext_vector_type(8)));
typedef short  s16x4 __attribute__((ext_vector_type(4)));
typedef float  f32x4 __attribute__((ext_vector_type(4)));
typedef float  f32x2 __attribute__((ext_vector_type(2)));

__device__ __forceinline__ unsigned short f2bf(float f) {
    unsigned int u = __builtin_bit_cast(unsigned int, f);
    u = (u + 0x7FFFu + ((u >> 16) & 1u)) >> 16;
    return (unsigned short)u;
}
__device__ __forceinline__ s16x8 ld8(const unsigned short* p) {
    return *(const s16x8*)p;   // 16B-aligned by construction
}

// ---------------- prep: K-blocked bf16 weights + padded mask ----------------
// wqkvB[ks][n][kk] = qkv_w[ks*32+kk][n]   (8 x 768 x 32 bf16, contiguous per ks)
// wprojB[ks][n][kk] = proj_w[ks*32+kk][n] (8 x 256 x 32 bf16)
// maskP[win][q][k]  (64x64x64 f32): pad keys k>=50 -> -1e30 (exp->0); pad queries -> 0
__global__ void prep_kernel(const float* __restrict__ qkv_w, const float* __restrict__ proj_w,
                            const float* __restrict__ mask,
                            unsigned short* __restrict__ wqkvB, unsigned short* __restrict__ wprojB,
                            float* __restrict__ maskP) {
    int idx = blockIdx.x * 256 + threadIdx.x;          // 0 .. 262143
    {
        int wv = idx >> 12, q = (idx >> 6) & 63, k = idx & 63;
        float v = (k < 50) ? ((q < 50) ? mask[(wv * 50 + q) * 50 + k] : 0.f) : -1e30f;
        maskP[idx] = v;
    }
    if (idx < 196608) {
        int ks = idx / 24576, rem = idx - ks * 24576, n = rem >> 5, kk = rem & 31;
        wqkvB[idx] = f2bf(qkv_w[(ks * 32 + kk) * 768 + n]);
    }
    if (idx < 65536) {
        int ks = idx >> 13, rem = idx & 8191, n = rem >> 5, kk = rem & 31;
        wprojB[idx] = f2bf(proj_w[(ks * 32 + kk) * 256 + n]);
    }
}

// ---------------- fully fused: QKV GEMM + attention + proj, one batch per block ----------------
// 1024 threads = 16 waves, LDS 152576 B (1 block/CU, 16 waves).
// Key idea: weight B-operands have no cross-wave reuse (N partitioned per wave), so they are
// loaded direct L2->register (1KB-coalesced dwordx4) -- ZERO barriers inside both K-loops.
// Only 3 barriers per block. O round-trips through LDS (aliases dead sXC); no global attO.
__global__ __launch_bounds__(1024, 4) void fused_kernel(
        const float* __restrict__ x, const float* __restrict__ cls,
        const float* __restrict__ qkv_b, const unsigned short* __restrict__ wqkvB,
        const unsigned short* __restrict__ wprojB, const float* __restrict__ proj_b,
        const float* __restrict__ maskP, float* __restrict__ out) {
    __shared__ __align__(16) char smem_raw[152576];
    unsigned short* S   = (unsigned short*)smem_raw;
    unsigned short* sXC = S;            // [64][264] xc bf16; later reused as sO (attention out)
    unsigned short* sQ  = S + 16896;    // [8][64][40]  (sP aliases dead half per head)
    unsigned short* sK  = S + 37376;    // [8][64][40]
    unsigned short* sVT = S + 57856;    // [8][32][72]  v^T [d][tok]

    const int b = blockIdx.x, tid = threadIdx.x;
    const int lane = tid & 63, w = tid >> 6;
    const int ln15 = lane & 15, quad = lane >> 4, q8 = quad * 8;
    const int win = b & 63;
    const float SCALE = 0.17677669529663687f;

    // ---- stage xc rows (row0=cls, 1..49=x, 50..63=0), paired u32 LDS writes
    #pragma unroll
    for (int i = 0; i < 8; ++i) {
        int p = i * 1024 + tid;
        int r = p >> 7, c = (p & 127) * 2;
        float v0, v1;
        if (r == 0)       { v0 = cls[c]; v1 = cls[c + 1]; }
        else if (r <= 49) { const float* px = &x[((size_t)b * 49 + (r - 1)) * 256 + c];
                            f32x2 t = *(const f32x2*)px; v0 = t[0]; v1 = t[1]; }
        else              { v0 = 0.f; v1 = 0.f; }
        *(unsigned int*)&sXC[r * 264 + c] = (unsigned int)f2bf(v0) | ((unsigned int)f2bf(v1) << 16);
    }
    // ---- prefetch phase-1 B frags for ks=0 (global->reg, overlaps barrier)
    s16x8 bcur[3];
    #pragma unroll
    for (int nt = 0; nt < 3; ++nt)
        bcur[nt] = ld8(wqkvB + (w * 48 + nt * 16 + ln15) * 32 + q8);
    __syncthreads();                                    // barrier 1

    // ================= phase 1: [64x256] @ [256x768], wave = 48 cols, barrier-free K-loop =====
    f32x4 acc[4][3];
    #pragma unroll
    for (int mt = 0; mt < 4; ++mt)
        #pragma unroll
        for (int nt = 0; nt < 3; ++nt) acc[mt][nt] = f32x4{0.f, 0.f, 0.f, 0.f};

    #pragma unroll
    for (int ks = 0; ks < 8; ++ks) {
        s16x8 bnext[3];
        if (ks < 7) {
            const unsigned short* src = wqkvB + (ks + 1) * 24576;
            #pragma unroll
            for (int nt = 0; nt < 3; ++nt)
                bnext[nt] = ld8(src + (w * 48 + nt * 16 + ln15) * 32 + q8);
        }
        s16x8 af[4];
        #pragma unroll
        for (int mt = 0; mt < 4; ++mt)
            af[mt] = ld8(&sXC[(mt * 16 + ln15) * 264 + ks * 32 + q8]);
        #pragma unroll
        for (int mt = 0; mt < 4; ++mt)
            #pragma unroll
            for (int nt = 0; nt < 3; ++nt)
                acc[mt][nt] = __builtin_amdgcn_mfma_f32_16x16x32_bf16(af[mt], bcur[nt], acc[mt][nt], 0, 0, 0);
        if (ks < 7) {
            #pragma unroll
            for (int nt = 0; nt < 3; ++nt) bcur[nt] = bnext[nt];
        }
    }

    // ---- epilogue: bias (+scale for q), scatter into sQ/sK, packed b64 into sVT
    #pragma unroll
    for (int nt = 0; nt < 3; ++nt) {
        const int gc = w * 48 + nt * 16 + ln15;
        const int type = (w * 48 + nt * 16) >> 8;       // wave-uniform
        const int hd = (gc >> 5) & 7, dd = gc & 31;
        const float bias = qkv_b[gc];
        if (type == 0) {
            #pragma unroll
            for (int mt = 0; mt < 4; ++mt)
                #pragma unroll
                for (int i = 0; i < 4; ++i)
                    sQ[hd * 2560 + (mt * 16 + quad * 4 + i) * 40 + dd] = f2bf((acc[mt][nt][i] + bias) * SCALE);
        } else if (type == 1) {
            #pragma unroll
            for (int mt = 0; mt < 4; ++mt)
                #pragma unroll
                for (int i = 0; i < 4; ++i)
                    sK[hd * 2560 + (mt * 16 + quad * 4 + i) * 40 + dd] = f2bf(acc[mt][nt][i] + bias);
        } else {
            #pragma unroll
            for (int mt = 0; mt < 4; ++mt) {
                s16x4 pk;
                #pragma unroll
                for (int i = 0; i < 4; ++i) pk[i] = f2bf(acc[mt][nt][i] + bias);
                *(s16x4*)&sVT[hd * 2304 + dd * 72 + mt * 16 + quad * 4] = pk;
            }
        }
    }
    __syncthreads();                                    // barrier 2

    // ================= phase 2: attention, wave = (head h, row-half rh), barrier-free =========
    {
        const int h = w >> 1, rh = w & 1, qt0 = rh * 2;
        // sP aliases this wave's own half of sQ[h]: writes [rh*1280, rh*1280+1152),
        // own bq reads are rows rh*32..rh*32+31 = [rh*1280,(rh+1)*1280) (read-before-write,
        // same-wave in-order DS); the sibling wave's ranges are disjoint.
        unsigned short* sPw = sQ + h * 2560 + rh * 1280;

        s16x8 ak[4];
        #pragma unroll
        for (int kt = 0; kt < 4; ++kt)
            ak[kt] = ld8(&sK[h * 2560 + (kt * 16 + ln15) * 40 + q8]);

        f32x4 st[2][4];
        #pragma unroll
        for (int mt = 0; mt < 2; ++mt) {
            s16x8 bq = ld8(&sQ[h * 2560 + ((qt0 + mt) * 16 + ln15) * 40 + q8]);
            #pragma unroll
            for (int kt = 0; kt < 4; ++kt) {
                f32x4 z = {0.f, 0.f, 0.f, 0.f};
                st[mt][kt] = __builtin_amdgcn_mfma_f32_16x16x32_bf16(ak[kt], bq, z, 0, 0, 0);
            }
        }
        // S^T layout: col(=lane&15)=query, row(=quad*4+reg)=key
        s16x8 pb[2][2];
        #pragma unroll
        for (int mt = 0; mt < 2; ++mt) {
            float sum = 0.f;
            #pragma unroll
            for (int kt = 0; kt < 4; ++kt) {
                f32x4 mk = *(const f32x4*)&maskP[((size_t)(win * 64 + (qt0 + mt) * 16 + ln15)) * 64 + kt * 16 + quad * 4];
                #pragma unroll
                for (int i = 0; i < 4; ++i) {
                    float e = __expf(st[mt][kt][i] + mk[i]);   // no-max softmax; pad keys -> 0
                    st[mt][kt][i] = e;
                    sum += e;
                }
            }
            sum += __shfl_xor(sum, 16, 64);
            sum += __shfl_xor(sum, 32, 64);
            const float inv = 1.f / sum;
            #pragma unroll
            for (int kt = 0; kt < 4; ++kt) {
                s16x4 pk;
                #pragma unroll
                for (int i = 0; i < 4; ++i) pk[i] = f2bf(st[mt][kt][i] * inv);
                *(s16x4*)&sPw[ln15 * 72 + kt * 16 + quad * 4] = pk;   // P[query][key]
            }
            asm volatile("s_waitcnt lgkmcnt(0)" ::: "memory");
            pb[mt][0] = ld8(&sPw[ln15 * 72 + q8]);        // B-frag: P[query=ln15][key=q8+j]
            pb[mt][1] = ld8(&sPw[ln15 * 72 + 32 + q8]);
        }
        // O^T = V^T @ P^T : C/D col=query, row=d
        s16x8 av[2][2];
        #pragma unroll
        for (int dt = 0; dt < 2; ++dt)
            #pragma unroll
            for (int kk = 0; kk < 2; ++kk)
                av[dt][kk] = ld8(&sVT[h * 2304 + (dt * 16 + ln15) * 72 + kk * 32 + q8]);
        f32x4 o[2][2];
        #pragma unroll
        for (int mt = 0; mt < 2; ++mt)
            #pragma unroll
            for (int dt = 0; dt < 2; ++dt) o[mt][dt] = f32x4{0.f, 0.f, 0.f, 0.f};
        #pragma unroll
        for (int mt = 0; mt < 2; ++mt)
            #pragma unroll
            for (int dt = 0; dt < 2; ++dt)
                #pragma unroll
                for (int kk = 0; kk < 2; ++kk)
                    o[mt][dt] = __builtin_amdgcn_mfma_f32_16x16x32_bf16(av[dt][kk], pb[mt][kk], o[mt][dt], 0, 0, 0);
        // O -> LDS (sO aliases sXC, dead after barrier 2); all 64 query rows (pads are finite)
        #pragma unroll
        for (int mt = 0; mt < 2; ++mt) {
            const int qg = (qt0 + mt) * 16 + ln15;
            #pragma unroll
            for (int dt = 0; dt < 2; ++dt) {
                s16x4 pk;
                #pragma unroll
                for (int i = 0; i < 4; ++i) pk[i] = f2bf(o[mt][dt][i]);
                *(s16x4*)&sXC[qg * 264 + h * 32 + dt * 16 + quad * 4] = pk;
            }
        }
    }
    __syncthreads();                                    // barrier 3

    // ================= phase 3: proj GEMM [64x256]@[256x256], barrier-free K-loop ==============
    {
        const int wm3 = w >> 3, wn3 = w & 7;            // wave tile: 32 rows x 32 cols
        s16x8 b3[2];
        #pragma unroll
        for (int nt = 0; nt < 2; ++nt)
            b3[nt] = ld8(wprojB + (wn3 * 32 + nt * 16 + ln15) * 32 + q8);
        f32x4 a3[2][2];
        #pragma unroll
        for (int mt = 0; mt < 2; ++mt)
            #pragma unroll
            for (int nt = 0; nt < 2; ++nt) a3[mt][nt] = f32x4{0.f, 0.f, 0.f, 0.f};
        #pragma unroll
        for (int ks = 0; ks < 8; ++ks) {
            s16x8 b3n[2];
            if (ks < 7) {
                const unsigned short* src = wprojB + (ks + 1) * 8192;
                #pragma unroll
                for (int nt = 0; nt < 2; ++nt)
                    b3n[nt] = ld8(src + (wn3 * 32 + nt * 16 + ln15) * 32 + q8);
            }
            s16x8 af3[2];
            #pragma unroll
            for (int mt = 0; mt < 2; ++mt)
                af3[mt] = ld8(&sXC[(wm3 * 32 + mt * 16 + ln15) * 264 + ks * 32 + q8]);
            #pragma unroll
            for (int mt = 0; mt < 2; ++mt)
                #pragma unroll
                for (int nt = 0; nt < 2; ++nt)
                    a3[mt][nt] = __builtin_amdgcn_mfma_f32_16x16x32_bf16(af3[mt], b3[nt], a3[mt][nt], 0, 0, 0);
            if (ks < 7) {
                #pragma unroll
                for (int nt = 0; nt < 2; ++nt) b3[nt] = b3n[nt];
            }
        }
        // epilogue: bias + split store (row 0 -> out[:,0], rows 1..49 -> out[:,1:])
        #pragma unroll
        for (int nt = 0; nt < 2; ++nt) {
            const int gc = wn3 * 32 + nt * 16 + ln15;
            const float bias = proj_b[gc];
            #pragma unroll
            for (int mt = 0; mt < 2; ++mt) {
                #pragma unroll
                for (int i = 0; i < 4; ++i) {
                    const int t = wm3 * 32 + mt * 16 + quad * 4 + i;
                    const float v = a3[mt][nt][i] + bias;
                    if (t == 0)      out[(size_t)b * 256 + gc] = v;
                    else if (t < 50) out[(size_t)524288 + ((size_t)b * 49 + (t - 1)) * 256 + gc] = v;
                }
            }
        }
    }
}

extern "C" void kernel_launch(void* const* d_in, const int* in_sizes, int n_in,
                              void* d_out, int out_size, void* d_ws, size_t ws_size,
                              hipStream_t stream) {
    const float* x      = (const float*)d_in[0];
    const float* mask   = (const float*)d_in[1];
    const float* cls    = (const float*)d_in[2];
    const float* qkv_w  = (const float*)d_in[3];
    const float* qkv_b  = (const float*)d_in[4];
    const float* proj_w = (const float*)d_in[5];
    const float* proj_b = (const float*)d_in[6];
    float* out = (float*)d_out;

    // workspace layout (1.57 MB)
    unsigned short* wqkvB  = (unsigned short*)d_ws;                        // 393,216 B
    unsigned short* wprojB = (unsigned short*)((char*)d_ws + 393216);      // 131,072 B
    float*          maskP  = (float*)((char*)d_ws + 524288);               // 1,048,576 B

    prep_kernel<<<1024, 256, 0, stream>>>(qkv_w, proj_w, mask, wqkvB, wprojB, maskP);
    fused_kernel<<<NB, 1024, 0, stream>>>(x, cls, qkv_b, wqkvB, wprojB, proj_b, maskP, out);
}